// Round 10
// baseline (13900.024 us; speedup 1.0000x reference)
//
#include <hip/hip_runtime.h>
#include <math.h>

typedef unsigned short ushort_t;
typedef unsigned int uint_t;

// ws offsets (floats)
#define OFF_XT    0          // XT[1600][64]: 0..63 y^T, 64..575 ctx^T, 576..1087 hs ping, 1088..1599 hs pong
#define OFF_CS    102400     // cs^T [512][64]
#define OFF_E     135168     // e[64][1024]
#define OFF_MD    200704     // [64][32][2] per-slice {m, D}
#define OFF_LENS  204800     // int[64]
#define OFF_CTR   204864     // int[128] per-step arrival counters
#define OFF_W2    204992     // W2[64][1024] = fc2w @ fc1w
#define OFF_B2    270528     // b2[64]
#define OFF_CP    270592     // N partials [64 b][32 slice][512 d]
#define OFF_HB16F 1319168    // h in bf16: 33,554,432 ushorts = 16,777,216 floats
#define WS_NEED   ((size_t)(1319168 + 16777216) * 4)

// out offsets (floats)
#define OUT_YH   0          // [64][128][64]
#define OUT_LENS 524288     // [64]
#define OUT_ATT  524352     // [64][1][128][1024]

__device__ __forceinline__ float sigf(float x) { return 1.0f / (1.0f + __expf(-x)); }
__device__ __forceinline__ float dot4(float4 a, float4 b) {
    return a.x * b.x + a.y * b.y + a.z * b.z + a.w * b.w;
}
__device__ __forceinline__ uint_t bf16rne(float x) {
    uint_t u = __float_as_uint(x);
    return (u + 0x7FFFu + ((u >> 16) & 1u)) >> 16;
}
#define BLO(u) __uint_as_float((u) << 16)
#define BHI(u) __uint_as_float((u) & 0xFFFF0000u)

// ---------------- init: XT, CS, lens, counters ----------------
__global__ void k_init(const float* __restrict__ h, float* __restrict__ ws) {
    int blk = blockIdx.x, tid = threadIdx.x;      // grid 528 x 256
    int idx = blk * 256 + tid;
    if (idx < 102400) {                           // XT: 1600*64
        int k = idx >> 6, b = idx & 63;
        float v = 0.0f;
        if (k == 0) v = 1.0f;                                    // one-hot SOS
        else if (k >= 64 && k < 576) v = h[(size_t)b * 524288 + (k - 64)];
        ws[OFF_XT + idx] = v;                                    // hs ping/pong rows -> 0
    }
    if (blk >= 400 && blk < 528)                  // CS: 32768 = 128*256
        ws[OFF_CS + (blk - 400) * 256 + tid] = 0.0f;
    if (blk == 527) {
        if (tid < 64) ((int*)ws)[OFF_LENS + tid] = 128;
        if (tid >= 64 && tid < 192) ((int*)ws)[OFF_CTR + tid - 64] = 0;
    }
}

// ---------------- h -> bf16 (once per launch) ----------------
__global__ void k_hconv(const float* __restrict__ h, float* __restrict__ ws) {
    size_t i = ((size_t)blockIdx.x * 256 + threadIdx.x) * 8;   // grid 16384 x 256
    float4 a = *(const float4*)(h + i);
    float4 b = *(const float4*)(h + i + 4);
    uint4 o;
    o.x = bf16rne(a.x) | (bf16rne(a.y) << 16);
    o.y = bf16rne(a.z) | (bf16rne(a.w) << 16);
    o.z = bf16rne(b.x) | (bf16rne(b.y) << 16);
    o.w = bf16rne(b.z) | (bf16rne(b.w) << 16);
    *(uint4*)((ushort_t*)(ws + OFF_HB16F) + i) = o;
}

// ---------------- fc2 o fc1 composition (once) ----------------
__global__ void k_fuse(const float* __restrict__ fc1w, const float* __restrict__ fc1b,
                       const float* __restrict__ fc2w, float* __restrict__ ws) {
    int blk = blockIdx.x;                         // 256 blocks
    int v = blk >> 2, kc = blk & 3;
    int k = kc * 256 + threadIdx.x;
    float acc = 0.0f;
#pragma unroll 8
    for (int m = 0; m < 128; m++) acc += fc2w[v * 128 + m] * fc1w[(size_t)m * 1024 + k];
    ws[OFF_W2 + (size_t)v * 1024 + k] = acc;
    if (kc == 0 && threadIdx.x == 0) {
        float bb = 0.0f;
        for (int m = 0; m < 128; m++) bb += fc2w[v * 128 + m] * fc1b[m];
        ws[OFF_B2 + v] = bb;
    }
}

// ---------------- gates (8 waves x K-eighth, float4 weights) + LSTM cell ----------------
// grid 256 x 512
__global__ void k_gates(const float* __restrict__ Wih, const float* __restrict__ Whh,
                        const float* __restrict__ bih, const float* __restrict__ bhh,
                        float* __restrict__ ws, int p) {
    const int tid = threadIdx.x;
    const int lane = tid & 63;
    const int w = tid >> 6;
    const int hs_in  = 576 + (p ? 512 : 0);
    const int hs_out = 576 + (p ? 0 : 512);
    __shared__ float gpart[4096];
    const int u0 = blockIdx.x * 2;
    const int wq = __builtin_amdgcn_readfirstlane(w);
    float acc[2][4] = {{0, 0, 0, 0}, {0, 0, 0, 0}};
    int k0 = wq * 136, k1 = k0 + 136;
    int kx1 = k1 < 576 ? k1 : 576;
#pragma unroll 2
    for (int k = k0; k < kx1; k += 4) {
        float4 xv;
        xv.x = ws[OFF_XT + (k + 0) * 64 + lane];
        xv.y = ws[OFF_XT + (k + 1) * 64 + lane];
        xv.z = ws[OFF_XT + (k + 2) * 64 + lane];
        xv.w = ws[OFF_XT + (k + 3) * 64 + lane];
#pragma unroll
        for (int uu = 0; uu < 2; ++uu)
#pragma unroll
            for (int g = 0; g < 4; ++g)
                acc[uu][g] += dot4(*(const float4*)&Wih[(size_t)(g * 512 + u0 + uu) * 576 + k], xv);
    }
    int kh0 = k0 > 576 ? k0 : 576;
#pragma unroll 2
    for (int k = kh0; k < k1; k += 4) {
        float4 xv;
        xv.x = ws[OFF_XT + (hs_in + (k - 576) + 0) * 64 + lane];
        xv.y = ws[OFF_XT + (hs_in + (k - 576) + 1) * 64 + lane];
        xv.z = ws[OFF_XT + (hs_in + (k - 576) + 2) * 64 + lane];
        xv.w = ws[OFF_XT + (hs_in + (k - 576) + 3) * 64 + lane];
#pragma unroll
        for (int uu = 0; uu < 2; ++uu)
#pragma unroll
            for (int g = 0; g < 4; ++g)
                acc[uu][g] += dot4(*(const float4*)&Whh[(size_t)(g * 512 + u0 + uu) * 512 + (k - 576)], xv);
    }
#pragma unroll
    for (int uu = 0; uu < 2; ++uu)
#pragma unroll
        for (int g = 0; g < 4; ++g)
            gpart[((w * 2 + uu) * 4 + g) * 64 + lane] = acc[uu][g];
    __syncthreads();
    if (tid < 128) {
        int uu = tid >> 6, b = tid & 63;
        int u = u0 + uu;
        float g4[4];
#pragma unroll
        for (int g = 0; g < 4; ++g) {
            float s = 0.0f;
#pragma unroll
            for (int ww = 0; ww < 8; ++ww) s += gpart[((ww * 2 + uu) * 4 + g) * 64 + b];
            g4[g] = s + bih[g * 512 + u] + bhh[g * 512 + u];
        }
        int idx = u * 64 + b;
        float co = ws[OFF_CS + idx];
        float I = sigf(g4[0]), F = sigf(g4[1]), G = tanhf(g4[2]), O = sigf(g4[3]);
        float cn = F * co + I * G;
        ws[OFF_CS + idx] = cn;
        ws[OFF_XT + (size_t)(hs_out + u) * 64 + b] = O * tanhf(cn);
    }
}

// ---------------- fused bf16 attn + comb (last-slice blocks finish) ----------------
// grid 2048, slice-major: sb = blk>>6 (0..31), b = blk&63; slice = 32 t-rows
__global__ void k_attn_comb(const int* __restrict__ slen, float* __restrict__ ws,
                            float* __restrict__ out, int p, int ts) {
    const int blk = blockIdx.x;
    const int tid = threadIdx.x;
    const int lane = tid & 63;
    const int w = tid >> 6;
    const int hs_out = 576 + (p ? 0 : 512);
    const int sb = blk >> 6, b = blk & 63;
    const int L = slen[b];
    const int t0 = sb * 32;
    __shared__ uint4 stage4[2048];       // 32 rows x 512 bf16 = 32 KB
    __shared__ float hs_sh[512];
    __shared__ float e_sh[32];
    __shared__ float wt_sh[32];
    ushort_t* stage = (ushort_t*)stage4;
    const ushort_t* hb = (const ushort_t*)(ws + OFF_HB16F) + ((size_t)b * 1024 + t0) * 512;
    // 8 back-to-back 16B loads (128B in flight); wave w holds rows {4j+w}, cols lane*8..
    uint4 r0 = *(const uint4*)(hb + 0 * 2048 + tid * 8);
    uint4 r1 = *(const uint4*)(hb + 1 * 2048 + tid * 8);
    uint4 r2 = *(const uint4*)(hb + 2 * 2048 + tid * 8);
    uint4 r3 = *(const uint4*)(hb + 3 * 2048 + tid * 8);
    uint4 r4 = *(const uint4*)(hb + 4 * 2048 + tid * 8);
    uint4 r5 = *(const uint4*)(hb + 5 * 2048 + tid * 8);
    uint4 r6 = *(const uint4*)(hb + 6 * 2048 + tid * 8);
    uint4 r7 = *(const uint4*)(hb + 7 * 2048 + tid * 8);
    hs_sh[tid]       = ws[OFF_XT + (size_t)(hs_out + tid) * 64 + b];
    hs_sh[256 + tid] = ws[OFF_XT + (size_t)(hs_out + 256 + tid) * 64 + b];
    __syncthreads();
    float hsv[8];
#pragma unroll
    for (int j = 0; j < 8; ++j) hsv[j] = hs_sh[lane * 8 + j];
#define EROW(J, R)                                                                  \
    {                                                                               \
        float part = BLO(R.x) * hsv[0] + BHI(R.x) * hsv[1]                          \
                   + BLO(R.y) * hsv[2] + BHI(R.y) * hsv[3]                          \
                   + BLO(R.z) * hsv[4] + BHI(R.z) * hsv[5]                          \
                   + BLO(R.w) * hsv[6] + BHI(R.w) * hsv[7];                         \
        _Pragma("unroll")                                                           \
        for (int mm = 1; mm < 64; mm <<= 1) part += __shfl_xor(part, mm);           \
        if (lane == 0) e_sh[4 * (J) + w] = part;                                    \
        *(uint4*)&stage[(J) * 2048 + tid * 8] = R;                                  \
    }
    EROW(0, r0) EROW(1, r1) EROW(2, r2) EROW(3, r3)
    EROW(4, r4) EROW(5, r5) EROW(6, r6) EROW(7, r7)
#undef EROW
    __syncthreads();                    // e_sh + stage ready
    float m_reg = 0.0f;
    if (tid < 32) {
        float m = e_sh[0];
#pragma unroll
        for (int j = 1; j < 32; ++j) m = fmaxf(m, e_sh[j]);
        m_reg = m;
        int tg = t0 + tid;
        wt_sh[tid] = (tg < L) ? __expf(e_sh[tid] - m) : 0.0f;
        ws[OFF_E + (size_t)b * 1024 + t0 + tid] = e_sh[tid];
    }
    __syncthreads();                    // wt_sh ready
    int nr = L - t0;
    nr = nr < 0 ? 0 : (nr > 32 ? 32 : nr);
    float accx = 0.0f, accy = 0.0f;
    const uint_t* st32 = (const uint_t*)stage;
    for (int tl = 0; tl < nr; ++tl) {
        float wt = wt_sh[tl];
        uint_t v = st32[tl * 256 + tid];
        accx += wt * BLO(v);
        accy += wt * BHI(v);
    }
    float2 o2; o2.x = accx; o2.y = accy;
    *(float2*)&ws[OFF_CP + (size_t)(b * 32 + sb) * 512 + tid * 2] = o2;
    if (tid == 0) {
        float D = 0.0f;
#pragma unroll
        for (int tl = 0; tl < 32; ++tl) D += wt_sh[tl];
        ws[OFF_MD + (b * 32 + sb) * 2]     = m_reg;
        ws[OFF_MD + (b * 32 + sb) * 2 + 1] = D;
    }
    __syncthreads();                    // all global writes issued (vmcnt drained)
    int* ctr = (int*)ws + OFF_CTR + ts;
    if (tid == 0)
        __hip_atomic_fetch_add(ctr, 1, __ATOMIC_RELEASE, __HIP_MEMORY_SCOPE_AGENT);
    if (sb != 31) return;

    // ---------- finisher: one block per b ----------
    if (tid == 0) {
        while (__hip_atomic_load(ctr, __ATOMIC_ACQUIRE, __HIP_MEMORY_SCOPE_AGENT) < 2048)
            __builtin_amdgcn_s_sleep(8);
    }
    __syncthreads();
    float* red   = (float*)stage4;        // [256]
    float* feat  = (float*)stage4 + 256;  // [1024]
    float* sc_sh = (float*)stage4 + 1280; // [32]
    float* lg_s  = (float*)stage4 + 1312; // [64]
    float mx = -INFINITY;
#pragma unroll
    for (int i = 0; i < 8; ++i) mx = fmaxf(mx, ws[OFF_MD + (tid + 256 * i) * 2]);
    red[tid] = mx;
    __syncthreads();
    for (int s = 128; s > 0; s >>= 1) {
        if (tid < s) red[tid] = fmaxf(red[tid], red[tid + s]);
        __syncthreads();
    }
    float m_g = red[0];
    __syncthreads();
    if (tid < 32) {
        float mi = ws[OFF_MD + (b * 32 + tid) * 2];
        float Di = ws[OFF_MD + (b * 32 + tid) * 2 + 1];
        float s = __expf(mi - m_g);
        sc_sh[tid] = s;
        red[tid] = s * Di;
    }
    __syncthreads();
    float dn = 0.0f;
#pragma unroll
    for (int j = 0; j < 32; ++j) dn += red[j];
    float inv = 1.0f / (dn + 1e-5f);
    float cx = 0.0f, cy = 0.0f;
#pragma unroll 4
    for (int i = 0; i < 32; ++i) {
        float s = sc_sh[i];
        float2 v = *(const float2*)&ws[OFF_CP + (size_t)(b * 32 + i) * 512 + tid * 2];
        cx += s * v.x;
        cy += s * v.y;
    }
    cx *= inv; cy *= inv;
    feat[512 + tid * 2] = cx;
    feat[512 + tid * 2 + 1] = cy;
    ws[OFF_XT + (size_t)(64 + tid * 2) * 64 + b] = cx;
    ws[OFF_XT + (size_t)(64 + tid * 2 + 1) * 64 + b] = cy;
    feat[tid * 2]     = ws[OFF_XT + (size_t)(hs_out + tid * 2) * 64 + b];
    feat[tid * 2 + 1] = ws[OFF_XT + (size_t)(hs_out + tid * 2 + 1) * 64 + b];
#pragma unroll
    for (int q = 0; q < 4; ++q) {
        int t = tid + 256 * q;
        float e = ws[OFF_E + (size_t)b * 1024 + t];
        float a = (t < L) ? __expf(e - m_g) * inv : 0.0f;
        out[OUT_ATT + (size_t)b * 131072 + (size_t)ts * 1024 + t] = a;
    }
    __syncthreads();
    int v = tid >> 2, qq = tid & 3;
    const float4* w4 = (const float4*)(ws + OFF_W2 + (size_t)v * 1024 + qq * 256);
    const float4* f4 = (const float4*)feat + qq * 64;
    float acc = 0.0f;
#pragma unroll 8
    for (int k = 0; k < 64; ++k) acc += dot4(w4[k], f4[k]);
    acc += __shfl_xor(acc, 1);
    acc += __shfl_xor(acc, 2);
    if (qq == 0) lg_s[v] = acc;
    __syncthreads();
    if (tid < 64) {
        float lg = lg_s[tid] + ws[OFF_B2 + tid];
        float mxv = lg;
#pragma unroll
        for (int mm = 1; mm < 64; mm <<= 1) mxv = fmaxf(mxv, __shfl_xor(mxv, mm));
        float ev = __expf(lg - mxv);
        float s = ev;
#pragma unroll
        for (int mm = 1; mm < 64; mm <<= 1) s += __shfl_xor(s, mm);
        float y = ev / s;
        out[OUT_YH + (size_t)b * 8192 + ts * 64 + tid] = y;
        ws[OFF_XT + (size_t)tid * 64 + b] = y;
        float av = lg;
        int ai = tid;
#pragma unroll
        for (int mm = 1; mm < 64; mm <<= 1) {
            float ov = __shfl_xor(av, mm);
            int oi = __shfl_xor(ai, mm);
            if (ov > av || (ov == av && oi < ai)) { av = ov; ai = oi; }
        }
        if (tid == 0) {
            int* lens = (int*)ws + OFF_LENS;
            if (ai == 1 && lens[b] > ts) lens[b] = ts + 1;   // EOS == 1
            if (ts == 127) out[OUT_LENS + b] = (float)lens[b];
        }
    }
}

// ---------------- f32 fallback attn (ns=16 geometry) ----------------
__global__ void k_attn(const float* __restrict__ h, const int* __restrict__ slen,
                       float* __restrict__ ws, int p) {
    const int blk = blockIdx.x;
    const int tid = threadIdx.x;
    const int lane = tid & 63;
    const int w = tid >> 6;
    const int hs_out = 576 + (p ? 0 : 512);
    const int b = blk >> 4, sb = blk & 15;
    const int L = slen[b];
    const int t0 = sb * 64;
    __shared__ float stage[4096];
    __shared__ float hs_sh[512];
    __shared__ float e_sh[8];
    const float* hb = h + ((size_t)b * 1024 + t0) * 512;
    hs_sh[tid]       = ws[OFF_XT + (size_t)(hs_out + tid) * 64 + b];
    hs_sh[256 + tid] = ws[OFF_XT + (size_t)(hs_out + 256 + tid) * 64 + b];
    __syncthreads();
    float hsv[8];
#pragma unroll
    for (int j = 0; j < 8; ++j) hsv[j] = hs_sh[lane * 8 + j];
    float m_run = -INFINITY, D = 0.0f, accx = 0.0f, accy = 0.0f;
    for (int c = 0; c < 8; ++c) {
        const float* gsrc = hb + (size_t)c * 4096 + tid * 4;
        float4 tv0 = *(const float4*)(gsrc);
        float4 tv1 = *(const float4*)(gsrc + 1024);
        float4 tv2 = *(const float4*)(gsrc + 2048);
        float4 tv3 = *(const float4*)(gsrc + 3072);
        __syncthreads();
        *(float4*)&stage[tid * 4]        = tv0;
        *(float4*)&stage[1024 + tid * 4] = tv1;
        *(float4*)&stage[2048 + tid * 4] = tv2;
        *(float4*)&stage[3072 + tid * 4] = tv3;
        __syncthreads();
#pragma unroll
        for (int rr = 0; rr < 2; ++rr) {
            int tl = w * 2 + rr;
            const float4* rp = (const float4*)&stage[tl * 512 + lane * 8];
            float4 pp = rp[0], qq = rp[1];
            float part = pp.x * hsv[0] + pp.y * hsv[1] + pp.z * hsv[2] + pp.w * hsv[3]
                       + qq.x * hsv[4] + qq.y * hsv[5] + qq.z * hsv[6] + qq.w * hsv[7];
#pragma unroll
            for (int mm = 1; mm < 64; mm <<= 1) part += __shfl_xor(part, mm);
            if (lane == 0) {
                e_sh[tl] = part;
                ws[OFF_E + (size_t)b * 1024 + t0 + c * 8 + tl] = part;
            }
        }
        __syncthreads();
        float cm = e_sh[0];
#pragma unroll
        for (int j = 1; j < 8; ++j) cm = fmaxf(cm, e_sh[j]);
        float m_new = fmaxf(m_run, cm);
        float sc = __expf(m_run - m_new);
        accx *= sc; accy *= sc; D *= sc;
        m_run = m_new;
#pragma unroll
        for (int tl = 0; tl < 8; ++tl) {
            int tg = t0 + c * 8 + tl;
            float wt = (tg < L) ? __expf(e_sh[tl] - m_run) : 0.0f;
            D += wt;
            float2 hv = *(const float2*)&stage[tl * 512 + tid * 2];
            accx += wt * hv.x;
            accy += wt * hv.y;
        }
    }
    float2 o2; o2.x = accx; o2.y = accy;
    *(float2*)&ws[OFF_CP + (size_t)(b * 16 + sb) * 512 + tid * 2] = o2;
    if (tid == 0) {
        ws[OFF_MD + (b * 16 + sb) * 2]     = m_run;
        ws[OFF_MD + (b * 16 + sb) * 2 + 1] = D;
    }
}

// ---------------- fallback combine ----------------
__global__ void k_comb(const int* __restrict__ slen, float* __restrict__ ws,
                       float* __restrict__ out, int p, int ts, int ns) {
    const int b = blockIdx.x, tid = threadIdx.x;
    const int hs_out = 576 + (p ? 0 : 512);
    __shared__ float red[256];
    __shared__ float feat[1024];
    __shared__ float sc_sh[32];
    __shared__ float lg_s[64];
    const int nent = 64 * ns;
    float mx = -INFINITY;
    for (int i = tid; i < nent; i += 256) mx = fmaxf(mx, ws[OFF_MD + i * 2]);
    red[tid] = mx;
    __syncthreads();
    for (int s = 128; s > 0; s >>= 1) {
        if (tid < s) red[tid] = fmaxf(red[tid], red[tid + s]);
        __syncthreads();
    }
    float m_g = red[0];
    __syncthreads();
    if (tid < ns) {
        float mi = ws[OFF_MD + (b * ns + tid) * 2];
        float Di = ws[OFF_MD + (b * ns + tid) * 2 + 1];
        float s = __expf(mi - m_g);
        sc_sh[tid] = s;
        red[tid] = s * Di;
    }
    __syncthreads();
    float dn = 0.0f;
    for (int j = 0; j < ns; ++j) dn += red[j];
    float inv = 1.0f / (dn + 1e-5f);
    float cx = 0.0f, cy = 0.0f;
    for (int i = 0; i < ns; ++i) {
        float s = sc_sh[i];
        float2 v = *(const float2*)&ws[OFF_CP + (size_t)(b * ns + i) * 512 + tid * 2];
        cx += s * v.x;
        cy += s * v.y;
    }
    cx *= inv; cy *= inv;
    feat[512 + tid * 2] = cx;
    feat[512 + tid * 2 + 1] = cy;
    ws[OFF_XT + (size_t)(64 + tid * 2) * 64 + b] = cx;
    ws[OFF_XT + (size_t)(64 + tid * 2 + 1) * 64 + b] = cy;
    feat[tid * 2]     = ws[OFF_XT + (size_t)(hs_out + tid * 2) * 64 + b];
    feat[tid * 2 + 1] = ws[OFF_XT + (size_t)(hs_out + tid * 2 + 1) * 64 + b];
    int L = slen[b];
#pragma unroll
    for (int q = 0; q < 4; ++q) {
        int t = tid + 256 * q;
        float e = ws[OFF_E + (size_t)b * 1024 + t];
        float a = (t < L) ? __expf(e - m_g) * inv : 0.0f;
        out[OUT_ATT + (size_t)b * 131072 + (size_t)ts * 1024 + t] = a;
    }
    __syncthreads();
    int v = tid >> 2, qq = tid & 3;
    const float4* w4 = (const float4*)(ws + OFF_W2 + (size_t)v * 1024 + qq * 256);
    const float4* f4 = (const float4*)feat + qq * 64;
    float acc = 0.0f;
#pragma unroll 8
    for (int k = 0; k < 64; ++k) acc += dot4(w4[k], f4[k]);
    acc += __shfl_xor(acc, 1);
    acc += __shfl_xor(acc, 2);
    if (qq == 0) lg_s[v] = acc;
    __syncthreads();
    if (tid < 64) {
        float lg = lg_s[tid] + ws[OFF_B2 + tid];
        float mxv = lg;
#pragma unroll
        for (int mm = 1; mm < 64; mm <<= 1) mxv = fmaxf(mxv, __shfl_xor(mxv, mm));
        float ev = __expf(lg - mxv);
        float s = ev;
#pragma unroll
        for (int mm = 1; mm < 64; mm <<= 1) s += __shfl_xor(s, mm);
        float y = ev / s;
        out[OUT_YH + (size_t)b * 8192 + ts * 64 + tid] = y;
        ws[OFF_XT + (size_t)tid * 64 + b] = y;
        float av = lg;
        int ai = tid;
#pragma unroll
        for (int mm = 1; mm < 64; mm <<= 1) {
            float ov = __shfl_xor(av, mm);
            int oi = __shfl_xor(ai, mm);
            if (ov > av || (ov == av && oi < ai)) { av = ov; ai = oi; }
        }
        if (tid == 0) {
            int* lens = (int*)ws + OFF_LENS;
            if (ai == 1 && lens[b] > ts) lens[b] = ts + 1;   // EOS == 1
            if (ts == 127) out[OUT_LENS + b] = (float)lens[b];
        }
    }
}

extern "C" void kernel_launch(void* const* d_in, const int* in_sizes, int n_in,
                              void* d_out, int out_size, void* d_ws, size_t ws_size,
                              hipStream_t stream) {
    (void)in_sizes; (void)n_in; (void)out_size;
    const float* h    = (const float*)d_in[0];
    const float* Wih  = (const float*)d_in[1];
    const float* Whh  = (const float*)d_in[2];
    const float* bih  = (const float*)d_in[3];
    const float* bhh  = (const float*)d_in[4];
    const float* fc1w = (const float*)d_in[5];
    const float* fc1b = (const float*)d_in[6];
    const float* fc2w = (const float*)d_in[7];
    const int*   slen = (const int*)d_in[8];
    float* ws  = (float*)d_ws;
    float* out = (float*)d_out;
    const bool use16 = (ws_size >= WS_NEED);

    k_init<<<528, 256, 0, stream>>>(h, ws);
    k_fuse<<<256, 256, 0, stream>>>(fc1w, fc1b, fc2w, ws);
    if (use16) k_hconv<<<16384, 256, 0, stream>>>(h, ws);
    for (int t = 0; t < 128; t++) {
        int p = t & 1;
        k_gates<<<256, 512, 0, stream>>>(Wih, Whh, bih, bhh, ws, p);
        if (use16) {
            k_attn_comb<<<2048, 256, 0, stream>>>(slen, ws, out, p, t);
        } else {
            k_attn<<<1024, 256, 0, stream>>>(h, slen, ws, p);
            k_comb<<<64, 256, 0, stream>>>(slen, ws, out, p, t, 16);
        }
    }
}

// Round 11
// 6112.323 us; speedup vs baseline: 2.2741x; 2.2741x over previous
//
#include <hip/hip_runtime.h>
#include <math.h>

typedef unsigned short ushort_t;
typedef unsigned int uint_t;

// ws offsets (floats)
#define OFF_XT    0          // XT[1600][64]: 0..63 y^T, 64..575 ctx^T, 576..1087 hs ping, 1088..1599 hs pong
#define OFF_CS    102400     // cs^T [512][64]
#define OFF_E     135168     // e[64][1024]
#define OFF_MD    200704     // [64][ns][2] per-slice {m, D}
#define OFF_LENS  204800     // int[64]
#define OFF_W2    204864     // W2[64][1024] = fc2w @ fc1w
#define OFF_B2    270400     // b2[64]
#define OFF_CP    270464     // N partials [64 b][32 slice][512 d]
#define OFF_HB16F 1319040    // h in bf16: 33,554,432 ushorts
#define WS_NEED   ((size_t)(1319040 + 16777216) * 4)

// out offsets (floats)
#define OUT_YH   0          // [64][128][64]
#define OUT_LENS 524288     // [64]
#define OUT_ATT  524352     // [64][1][128][1024]

__device__ __forceinline__ float sigf(float x) { return 1.0f / (1.0f + __expf(-x)); }
__device__ __forceinline__ float dot4(float4 a, float4 b) {
    return a.x * b.x + a.y * b.y + a.z * b.z + a.w * b.w;
}
__device__ __forceinline__ uint_t bf16rne(float x) {
    uint_t u = __float_as_uint(x);
    return (u + 0x7FFFu + ((u >> 16) & 1u)) >> 16;
}
#define BLO(u) __uint_as_float((u) << 16)
#define BHI(u) __uint_as_float((u) & 0xFFFF0000u)

// ---------------- init: XT, CS, lens ----------------
__global__ void k_init(const float* __restrict__ h, float* __restrict__ ws) {
    int blk = blockIdx.x, tid = threadIdx.x;      // grid 528 x 256
    int idx = blk * 256 + tid;
    if (idx < 102400) {                           // XT: 1600*64
        int k = idx >> 6, b = idx & 63;
        float v = 0.0f;
        if (k == 0) v = 1.0f;                                    // one-hot SOS
        else if (k >= 64 && k < 576) v = h[(size_t)b * 524288 + (k - 64)];
        ws[OFF_XT + idx] = v;                                    // hs ping/pong rows -> 0
    }
    if (blk >= 400 && blk < 528)                  // CS: 32768 = 128*256
        ws[OFF_CS + (blk - 400) * 256 + tid] = 0.0f;
    if (blk == 527 && tid < 64) ((int*)ws)[OFF_LENS + tid] = 128;
}

// ---------------- h -> bf16 (once per launch) ----------------
__global__ void k_hconv(const float* __restrict__ h, float* __restrict__ ws) {
    size_t i = ((size_t)blockIdx.x * 256 + threadIdx.x) * 8;   // grid 16384 x 256
    float4 a = *(const float4*)(h + i);
    float4 b = *(const float4*)(h + i + 4);
    uint4 o;
    o.x = bf16rne(a.x) | (bf16rne(a.y) << 16);
    o.y = bf16rne(a.z) | (bf16rne(a.w) << 16);
    o.z = bf16rne(b.x) | (bf16rne(b.y) << 16);
    o.w = bf16rne(b.z) | (bf16rne(b.w) << 16);
    *(uint4*)((ushort_t*)(ws + OFF_HB16F) + i) = o;
}

// ---------------- fc2 o fc1 composition (once) ----------------
__global__ void k_fuse(const float* __restrict__ fc1w, const float* __restrict__ fc1b,
                       const float* __restrict__ fc2w, float* __restrict__ ws) {
    int blk = blockIdx.x;                         // 256 blocks
    int v = blk >> 2, kc = blk & 3;
    int k = kc * 256 + threadIdx.x;
    float acc = 0.0f;
#pragma unroll 8
    for (int m = 0; m < 128; m++) acc += fc2w[v * 128 + m] * fc1w[(size_t)m * 1024 + k];
    ws[OFF_W2 + (size_t)v * 1024 + k] = acc;
    if (kc == 0 && threadIdx.x == 0) {
        float bb = 0.0f;
        for (int m = 0; m < 128; m++) bb += fc2w[v * 128 + m] * fc1b[m];
        ws[OFF_B2 + v] = bb;
    }
}

// ---------------- gates (16 waves x K-sixteenth) + LSTM cell ----------------
// grid 256 x 1024
__global__ __launch_bounds__(1024) void k_gates(
        const float* __restrict__ Wih, const float* __restrict__ Whh,
        const float* __restrict__ bih, const float* __restrict__ bhh,
        float* __restrict__ ws, int p) {
    const int tid = threadIdx.x;
    const int lane = tid & 63;
    const int w = tid >> 6;
    const int hs_in  = 576 + (p ? 512 : 0);
    const int hs_out = 576 + (p ? 0 : 512);
    __shared__ float gpart[8192];                 // [16 w][2 uu][4 g][64 b]
    const int u0 = blockIdx.x * 2;
    const int wq = __builtin_amdgcn_readfirstlane(w);
    float acc[2][4] = {{0, 0, 0, 0}, {0, 0, 0, 0}};
    int k0 = wq * 68, k1 = k0 + 68;
    int kx1 = k1 < 576 ? k1 : 576;
#pragma unroll 2
    for (int k = k0; k < kx1; k += 4) {
        float4 xv;
        xv.x = ws[OFF_XT + (k + 0) * 64 + lane];
        xv.y = ws[OFF_XT + (k + 1) * 64 + lane];
        xv.z = ws[OFF_XT + (k + 2) * 64 + lane];
        xv.w = ws[OFF_XT + (k + 3) * 64 + lane];
#pragma unroll
        for (int uu = 0; uu < 2; ++uu)
#pragma unroll
            for (int g = 0; g < 4; ++g)
                acc[uu][g] += dot4(*(const float4*)&Wih[(size_t)(g * 512 + u0 + uu) * 576 + k], xv);
    }
    int kh0 = k0 > 576 ? k0 : 576;
#pragma unroll 2
    for (int k = kh0; k < k1; k += 4) {
        float4 xv;
        xv.x = ws[OFF_XT + (hs_in + (k - 576) + 0) * 64 + lane];
        xv.y = ws[OFF_XT + (hs_in + (k - 576) + 1) * 64 + lane];
        xv.z = ws[OFF_XT + (hs_in + (k - 576) + 2) * 64 + lane];
        xv.w = ws[OFF_XT + (hs_in + (k - 576) + 3) * 64 + lane];
#pragma unroll
        for (int uu = 0; uu < 2; ++uu)
#pragma unroll
            for (int g = 0; g < 4; ++g)
                acc[uu][g] += dot4(*(const float4*)&Whh[(size_t)(g * 512 + u0 + uu) * 512 + (k - 576)], xv);
    }
#pragma unroll
    for (int uu = 0; uu < 2; ++uu)
#pragma unroll
        for (int g = 0; g < 4; ++g)
            gpart[((w * 2 + uu) * 4 + g) * 64 + lane] = acc[uu][g];
    __syncthreads();
    if (tid < 128) {
        int uu = tid >> 6, b = tid & 63;
        int u = u0 + uu;
        float g4[4];
#pragma unroll
        for (int g = 0; g < 4; ++g) {
            float s = 0.0f;
#pragma unroll
            for (int ww = 0; ww < 16; ++ww) s += gpart[((ww * 2 + uu) * 4 + g) * 64 + b];
            g4[g] = s + bih[g * 512 + u] + bhh[g * 512 + u];
        }
        int idx = u * 64 + b;
        float co = ws[OFF_CS + idx];
        float I = sigf(g4[0]), F = sigf(g4[1]), G = tanhf(g4[2]), O = sigf(g4[3]);
        float cn = F * co + I * G;
        ws[OFF_CS + idx] = cn;
        ws[OFF_XT + (size_t)(hs_out + u) * 64 + b] = O * tanhf(cn);
    }
}

// ---------------- bf16 attn: reg-resident rows, in-reg PV, ~3KB LDS ----------------
// grid 2048 = b*32 + sb, block 256 (4 waves); slice = 32 t-rows
// wave w owns cols [w*128, w*128+128); lane = 16*rg + cl holds rows rg*8+j, cols cl*8..+7
__global__ __launch_bounds__(256) void k_attn16(const int* __restrict__ slen,
                                                float* __restrict__ ws, int p) {
    const int blk = blockIdx.x;
    const int tid = threadIdx.x;
    const int lane = tid & 63;
    const int w = __builtin_amdgcn_readfirstlane(tid >> 6);
    const int rg = lane >> 4, cl = lane & 15;
    const int hs_out = 576 + (p ? 0 : 512);
    const int b = blk >> 5, sb = blk & 31;
    const int L = slen[b];
    const int t0 = sb * 32;
    __shared__ float hs_sh[512];
    __shared__ float e_part[128];   // [4 w][32 rows]
    __shared__ float e_sh[32];
    __shared__ float wt_sh[32];
    const ushort_t* hb = (const ushort_t*)(ws + OFF_HB16F)
                       + ((size_t)b * 1024 + t0) * 512 + w * 128 + cl * 8;
    // 8 back-to-back 16B loads: rows rg*8+j
    uint4 r0 = *(const uint4*)(hb + (size_t)(rg * 8 + 0) * 512);
    uint4 r1 = *(const uint4*)(hb + (size_t)(rg * 8 + 1) * 512);
    uint4 r2 = *(const uint4*)(hb + (size_t)(rg * 8 + 2) * 512);
    uint4 r3 = *(const uint4*)(hb + (size_t)(rg * 8 + 3) * 512);
    uint4 r4 = *(const uint4*)(hb + (size_t)(rg * 8 + 4) * 512);
    uint4 r5 = *(const uint4*)(hb + (size_t)(rg * 8 + 5) * 512);
    uint4 r6 = *(const uint4*)(hb + (size_t)(rg * 8 + 6) * 512);
    uint4 r7 = *(const uint4*)(hb + (size_t)(rg * 8 + 7) * 512);
    hs_sh[tid]       = ws[OFF_XT + (size_t)(hs_out + tid) * 64 + b];
    hs_sh[256 + tid] = ws[OFF_XT + (size_t)(hs_out + 256 + tid) * 64 + b];
    __syncthreads();
    float hsv[8];
#pragma unroll
    for (int j = 0; j < 8; ++j) hsv[j] = hs_sh[w * 128 + cl * 8 + j];
    // e partial per row: reduce over 16 lanes (cl) of each rg group
#define EROW(J, R)                                                                  \
    {                                                                               \
        float part = BLO(R.x) * hsv[0] + BHI(R.x) * hsv[1]                          \
                   + BLO(R.y) * hsv[2] + BHI(R.y) * hsv[3]                          \
                   + BLO(R.z) * hsv[4] + BHI(R.z) * hsv[5]                          \
                   + BLO(R.w) * hsv[6] + BHI(R.w) * hsv[7];                         \
        part += __shfl_xor(part, 1);                                                \
        part += __shfl_xor(part, 2);                                                \
        part += __shfl_xor(part, 4);                                                \
        part += __shfl_xor(part, 8);                                                \
        if (cl == 0) e_part[w * 32 + rg * 8 + (J)] = part;                          \
    }
    EROW(0, r0) EROW(1, r1) EROW(2, r2) EROW(3, r3)
    EROW(4, r4) EROW(5, r5) EROW(6, r6) EROW(7, r7)
#undef EROW
    __syncthreads();
    if (tid < 32) {
        float e = e_part[tid] + e_part[32 + tid] + e_part[64 + tid] + e_part[96 + tid];
        e_sh[tid] = e;
        ws[OFF_E + (size_t)b * 1024 + t0 + tid] = e;
    }
    __syncthreads();
    if (tid < 32) {
        float m = e_sh[0];
#pragma unroll
        for (int j = 1; j < 32; ++j) m = fmaxf(m, e_sh[j]);
        int tg = t0 + tid;
        wt_sh[tid] = (tg < L) ? __expf(e_sh[tid] - m) : 0.0f;
        if (tid == 0) ws[OFF_MD + (b * 32 + sb) * 2] = m;
    }
    __syncthreads();
    // PV from registers: acc over this thread's 8 rows
    float acc[8] = {0, 0, 0, 0, 0, 0, 0, 0};
#define PVROW(J, R)                                                                 \
    {                                                                               \
        float wt = wt_sh[rg * 8 + (J)];                                             \
        acc[0] += wt * BLO(R.x); acc[1] += wt * BHI(R.x);                           \
        acc[2] += wt * BLO(R.y); acc[3] += wt * BHI(R.y);                           \
        acc[4] += wt * BLO(R.z); acc[5] += wt * BHI(R.z);                           \
        acc[6] += wt * BLO(R.w); acc[7] += wt * BHI(R.w);                           \
    }
    PVROW(0, r0) PVROW(1, r1) PVROW(2, r2) PVROW(3, r3)
    PVROW(4, r4) PVROW(5, r5) PVROW(6, r6) PVROW(7, r7)
#undef PVROW
    // reduce across rg groups (lanes lane^16, lane^32)
#pragma unroll
    for (int k = 0; k < 8; ++k) {
        acc[k] += __shfl_xor(acc[k], 16);
        acc[k] += __shfl_xor(acc[k], 32);
    }
    if (rg == 0) {
        float4 o0; o0.x = acc[0]; o0.y = acc[1]; o0.z = acc[2]; o0.w = acc[3];
        float4 o1; o1.x = acc[4]; o1.y = acc[5]; o1.z = acc[6]; o1.w = acc[7];
        float* cp = ws + OFF_CP + (size_t)(b * 32 + sb) * 512 + w * 128 + cl * 8;
        *(float4*)cp = o0;
        *(float4*)(cp + 4) = o1;
    }
    if (tid == 0) {
        float D = 0.0f;
#pragma unroll
        for (int tl = 0; tl < 32; ++tl) D += wt_sh[tl];
        ws[OFF_MD + (b * 32 + sb) * 2 + 1] = D;
    }
}

// ---------------- f32 fallback attn (ns=16 geometry) ----------------
__global__ void k_attn(const float* __restrict__ h, const int* __restrict__ slen,
                       float* __restrict__ ws, int p) {
    const int blk = blockIdx.x;
    const int tid = threadIdx.x;
    const int lane = tid & 63;
    const int w = tid >> 6;
    const int hs_out = 576 + (p ? 0 : 512);
    const int b = blk >> 4, sb = blk & 15;
    const int L = slen[b];
    const int t0 = sb * 64;
    __shared__ float stage[4096];
    __shared__ float hs_sh[512];
    __shared__ float e_sh[8];
    const float* hb = h + ((size_t)b * 1024 + t0) * 512;
    hs_sh[tid]       = ws[OFF_XT + (size_t)(hs_out + tid) * 64 + b];
    hs_sh[256 + tid] = ws[OFF_XT + (size_t)(hs_out + 256 + tid) * 64 + b];
    __syncthreads();
    float hsv[8];
#pragma unroll
    for (int j = 0; j < 8; ++j) hsv[j] = hs_sh[lane * 8 + j];
    float m_run = -INFINITY, D = 0.0f, accx = 0.0f, accy = 0.0f;
    for (int c = 0; c < 8; ++c) {
        const float* gsrc = hb + (size_t)c * 4096 + tid * 4;
        float4 tv0 = *(const float4*)(gsrc);
        float4 tv1 = *(const float4*)(gsrc + 1024);
        float4 tv2 = *(const float4*)(gsrc + 2048);
        float4 tv3 = *(const float4*)(gsrc + 3072);
        __syncthreads();
        *(float4*)&stage[tid * 4]        = tv0;
        *(float4*)&stage[1024 + tid * 4] = tv1;
        *(float4*)&stage[2048 + tid * 4] = tv2;
        *(float4*)&stage[3072 + tid * 4] = tv3;
        __syncthreads();
#pragma unroll
        for (int rr = 0; rr < 2; ++rr) {
            int tl = w * 2 + rr;
            const float4* rp = (const float4*)&stage[tl * 512 + lane * 8];
            float4 pp = rp[0], qq = rp[1];
            float part = pp.x * hsv[0] + pp.y * hsv[1] + pp.z * hsv[2] + pp.w * hsv[3]
                       + qq.x * hsv[4] + qq.y * hsv[5] + qq.z * hsv[6] + qq.w * hsv[7];
#pragma unroll
            for (int mm = 1; mm < 64; mm <<= 1) part += __shfl_xor(part, mm);
            if (lane == 0) {
                e_sh[tl] = part;
                ws[OFF_E + (size_t)b * 1024 + t0 + c * 8 + tl] = part;
            }
        }
        __syncthreads();
        float cm = e_sh[0];
#pragma unroll
        for (int j = 1; j < 8; ++j) cm = fmaxf(cm, e_sh[j]);
        float m_new = fmaxf(m_run, cm);
        float sc = __expf(m_run - m_new);
        accx *= sc; accy *= sc; D *= sc;
        m_run = m_new;
#pragma unroll
        for (int tl = 0; tl < 8; ++tl) {
            int tg = t0 + c * 8 + tl;
            float wt = (tg < L) ? __expf(e_sh[tl] - m_run) : 0.0f;
            D += wt;
            float2 hv = *(const float2*)&stage[tl * 512 + tid * 2];
            accx += wt * hv.x;
            accy += wt * hv.y;
        }
    }
    float2 o2; o2.x = accx; o2.y = accy;
    *(float2*)&ws[OFF_CP + (size_t)(b * 16 + sb) * 512 + tid * 2] = o2;
    if (tid == 0) {
        ws[OFF_MD + (b * 16 + sb) * 2]     = m_run;
        ws[OFF_MD + (b * 16 + sb) * 2 + 1] = D;
    }
}

// ---------------- combine (global max) + attentions + head + lens + x update ----
// grid 64 x 256; ns = slices per batch (32 bf16 path, 16 f32 path)
__global__ void k_comb(const int* __restrict__ slen, float* __restrict__ ws,
                       float* __restrict__ out, int p, int ts, int ns) {
    const int b = blockIdx.x, tid = threadIdx.x;
    const int hs_out = 576 + (p ? 0 : 512);
    __shared__ float red[256];
    __shared__ float feat[1024];
    __shared__ float sc_sh[32];
    __shared__ float lg_s[64];
    const int nent = 64 * ns;
    float mx = -INFINITY;
    for (int i = tid; i < nent; i += 256) mx = fmaxf(mx, ws[OFF_MD + i * 2]);
    red[tid] = mx;
    __syncthreads();
    for (int s = 128; s > 0; s >>= 1) {
        if (tid < s) red[tid] = fmaxf(red[tid], red[tid + s]);
        __syncthreads();
    }
    float m_g = red[0];
    __syncthreads();
    if (tid < ns) {
        float mi = ws[OFF_MD + (b * ns + tid) * 2];
        float Di = ws[OFF_MD + (b * ns + tid) * 2 + 1];
        float s = __expf(mi - m_g);
        sc_sh[tid] = s;
        red[tid] = s * Di;
    }
    __syncthreads();
    float dn = 0.0f;
    for (int j = 0; j < ns; ++j) dn += red[j];
    float inv = 1.0f / (dn + 1e-5f);
    float cx = 0.0f, cy = 0.0f;
    for (int i = 0; i < ns; ++i) {
        float s = sc_sh[i];
        float2 v = *(const float2*)&ws[OFF_CP + (size_t)(b * ns + i) * 512 + tid * 2];
        cx += s * v.x;
        cy += s * v.y;
    }
    cx *= inv; cy *= inv;
    feat[512 + tid * 2] = cx;
    feat[512 + tid * 2 + 1] = cy;
    ws[OFF_XT + (size_t)(64 + tid * 2) * 64 + b] = cx;
    ws[OFF_XT + (size_t)(64 + tid * 2 + 1) * 64 + b] = cy;
    feat[tid * 2]     = ws[OFF_XT + (size_t)(hs_out + tid * 2) * 64 + b];
    feat[tid * 2 + 1] = ws[OFF_XT + (size_t)(hs_out + tid * 2 + 1) * 64 + b];
    int L = slen[b];
#pragma unroll
    for (int q = 0; q < 4; ++q) {
        int t = tid + 256 * q;
        float e = ws[OFF_E + (size_t)b * 1024 + t];
        float a = (t < L) ? __expf(e - m_g) * inv : 0.0f;
        out[OUT_ATT + (size_t)b * 131072 + (size_t)ts * 1024 + t] = a;
    }
    __syncthreads();
    int v = tid >> 2, qq = tid & 3;
    const float4* w4 = (const float4*)(ws + OFF_W2 + (size_t)v * 1024 + qq * 256);
    const float4* f4 = (const float4*)feat + qq * 64;
    float acc = 0.0f;
#pragma unroll 8
    for (int k = 0; k < 64; ++k) acc += dot4(w4[k], f4[k]);
    acc += __shfl_xor(acc, 1);
    acc += __shfl_xor(acc, 2);
    if (qq == 0) lg_s[v] = acc;
    __syncthreads();
    if (tid < 64) {
        float lg = lg_s[tid] + ws[OFF_B2 + tid];
        float mxv = lg;
#pragma unroll
        for (int mm = 1; mm < 64; mm <<= 1) mxv = fmaxf(mxv, __shfl_xor(mxv, mm));
        float ev = __expf(lg - mxv);
        float s = ev;
#pragma unroll
        for (int mm = 1; mm < 64; mm <<= 1) s += __shfl_xor(s, mm);
        float y = ev / s;
        out[OUT_YH + (size_t)b * 8192 + ts * 64 + tid] = y;
        ws[OFF_XT + (size_t)tid * 64 + b] = y;
        float av = lg;
        int ai = tid;
#pragma unroll
        for (int mm = 1; mm < 64; mm <<= 1) {
            float ov = __shfl_xor(av, mm);
            int oi = __shfl_xor(ai, mm);
            if (ov > av || (ov == av && oi < ai)) { av = ov; ai = oi; }
        }
        if (tid == 0) {
            int* lens = (int*)ws + OFF_LENS;
            if (ai == 1 && lens[b] > ts) lens[b] = ts + 1;   // EOS == 1
            if (ts == 127) out[OUT_LENS + b] = (float)lens[b];
        }
    }
}

extern "C" void kernel_launch(void* const* d_in, const int* in_sizes, int n_in,
                              void* d_out, int out_size, void* d_ws, size_t ws_size,
                              hipStream_t stream) {
    (void)in_sizes; (void)n_in; (void)out_size;
    const float* h    = (const float*)d_in[0];
    const float* Wih  = (const float*)d_in[1];
    const float* Whh  = (const float*)d_in[2];
    const float* bih  = (const float*)d_in[3];
    const float* bhh  = (const float*)d_in[4];
    const float* fc1w = (const float*)d_in[5];
    const float* fc1b = (const float*)d_in[6];
    const float* fc2w = (const float*)d_in[7];
    const int*   slen = (const int*)d_in[8];
    float* ws  = (float*)d_ws;
    float* out = (float*)d_out;
    const bool use16 = (ws_size >= WS_NEED);

    k_init<<<528, 256, 0, stream>>>(h, ws);
    k_fuse<<<256, 256, 0, stream>>>(fc1w, fc1b, fc2w, ws);
    if (use16) k_hconv<<<16384, 256, 0, stream>>>(h, ws);
    for (int t = 0; t < 128; t++) {
        int p = t & 1;
        k_gates<<<256, 1024, 0, stream>>>(Wih, Whh, bih, bhh, ws, p);
        if (use16) {
            k_attn16<<<2048, 256, 0, stream>>>(slen, ws, p);
            k_comb<<<64, 256, 0, stream>>>(slen, ws, out, p, t, 32);
        } else {
            k_attn<<<1024, 256, 0, stream>>>(h, slen, ws, p);
            k_comb<<<64, 256, 0, stream>>>(slen, ws, out, p, t, 16);
        }
    }
}

// Round 12
// 5293.256 us; speedup vs baseline: 2.6260x; 1.1547x over previous
//
#include <hip/hip_runtime.h>
#include <math.h>

typedef unsigned short ushort_t;
typedef unsigned int uint_t;

// ws offsets (floats)
#define OFF_XT    0          // XT[1600][64]: 0..63 y^T, 64..575 ctx^T, 576..1087 hs
#define OFF_CS    102400     // cs^T [512][64]
#define OFF_E     135168     // e[64][1024]
#define OFF_MD    200704     // [64][ns][2] per-slice {m, D}
#define OFF_LENS  204800     // int[64]
#define OFF_W2    204864     // W2[64][1024] = fc2w @ fc1w
#define OFF_B2    270400     // b2[64]
#define OFF_CP    270464     // N partials [64 b][32 slice][512 d]
#define OFF_GHH   1319040    // ghh[2048 r][64 b] = Whh@hs + bih + bhh
#define OFF_HB16F 1450112    // h in bf16: 33,554,432 ushorts
#define WS_NEED   ((size_t)(1450112 + 16777216) * 4)

// out offsets (floats)
#define OUT_YH   0          // [64][128][64]
#define OUT_LENS 524288     // [64]
#define OUT_ATT  524352     // [64][1][128][1024]

__device__ __forceinline__ float sigf(float x) { return 1.0f / (1.0f + __expf(-x)); }
__device__ __forceinline__ float dot4(float4 a, float4 b) {
    return a.x * b.x + a.y * b.y + a.z * b.z + a.w * b.w;
}
__device__ __forceinline__ uint_t bf16rne(float x) {
    uint_t u = __float_as_uint(x);
    return (u + 0x7FFFu + ((u >> 16) & 1u)) >> 16;
}
#define BLO(u) __uint_as_float((u) << 16)
#define BHI(u) __uint_as_float((u) & 0xFFFF0000u)

// ---------------- init: XT, CS, lens ----------------
__global__ void k_init(const float* __restrict__ h, float* __restrict__ ws) {
    int blk = blockIdx.x, tid = threadIdx.x;      // grid 528 x 256
    int idx = blk * 256 + tid;
    if (idx < 102400) {                           // XT: 1600*64
        int k = idx >> 6, b = idx & 63;
        float v = 0.0f;
        if (k == 0) v = 1.0f;                                    // one-hot SOS
        else if (k >= 64 && k < 576) v = h[(size_t)b * 524288 + (k - 64)];
        ws[OFF_XT + idx] = v;                                    // hs rows -> 0
    }
    if (blk >= 400 && blk < 528)                  // CS: 32768 = 128*256
        ws[OFF_CS + (blk - 400) * 256 + tid] = 0.0f;
    if (blk == 527 && tid < 64) ((int*)ws)[OFF_LENS + tid] = 128;
}

// ---------------- h -> bf16 (once per launch) ----------------
__global__ void k_hconv(const float* __restrict__ h, float* __restrict__ ws) {
    size_t i = ((size_t)blockIdx.x * 256 + threadIdx.x) * 8;   // grid 16384 x 256
    float4 a = *(const float4*)(h + i);
    float4 b = *(const float4*)(h + i + 4);
    uint4 o;
    o.x = bf16rne(a.x) | (bf16rne(a.y) << 16);
    o.y = bf16rne(a.z) | (bf16rne(a.w) << 16);
    o.z = bf16rne(b.x) | (bf16rne(b.y) << 16);
    o.w = bf16rne(b.z) | (bf16rne(b.w) << 16);
    *(uint4*)((ushort_t*)(ws + OFF_HB16F) + i) = o;
}

// ---------------- fc2 o fc1 composition + ghh=bias init (once) ----------------
__global__ void k_fuse(const float* __restrict__ fc1w, const float* __restrict__ fc1b,
                       const float* __restrict__ fc2w, const float* __restrict__ bih,
                       const float* __restrict__ bhh, float* __restrict__ ws) {
    int blk = blockIdx.x;                         // 256 blocks
    int v = blk >> 2, kc = blk & 3;
    int k = kc * 256 + threadIdx.x;
    float acc = 0.0f;
#pragma unroll 8
    for (int m = 0; m < 128; m++) acc += fc2w[v * 128 + m] * fc1w[(size_t)m * 1024 + k];
    ws[OFF_W2 + (size_t)v * 1024 + k] = acc;
    if (kc == 0 && threadIdx.x == 0) {
        float bb = 0.0f;
        for (int m = 0; m < 128; m++) bb += fc2w[v * 128 + m] * fc1b[m];
        ws[OFF_B2 + v] = bb;
    }
    // ghh init = bih + bhh (hs(-1)=0): 2048x64 entries, 2 per thread
#pragma unroll
    for (int rep = 0; rep < 2; ++rep) {
        int idx = (blk * 256 + threadIdx.x) * 2 + rep;
        int r = idx >> 6;
        ws[OFF_GHH + idx] = bih[r] + bhh[r];
    }
}

// ---------------- gates_x: Wih.x + ghh -> cell -> hs (rows 576) ----------------
// grid 256 x 512 (8 waves x K-chunk 72)
__global__ __launch_bounds__(512) void k_gatesx(const float* __restrict__ Wih,
                                                float* __restrict__ ws) {
    const int tid = threadIdx.x;
    const int lane = tid & 63;
    const int w = tid >> 6;
    __shared__ float gpart[4096];                 // [8 w][2 uu][4 g][64 b]
    const int u0 = blockIdx.x * 2;
    const int wq = __builtin_amdgcn_readfirstlane(w);
    float acc[2][4] = {{0, 0, 0, 0}, {0, 0, 0, 0}};
    int k0 = wq * 72, k1 = k0 + 72;
#pragma unroll 2
    for (int k = k0; k < k1; k += 4) {
        float4 xv;
        xv.x = ws[OFF_XT + (k + 0) * 64 + lane];
        xv.y = ws[OFF_XT + (k + 1) * 64 + lane];
        xv.z = ws[OFF_XT + (k + 2) * 64 + lane];
        xv.w = ws[OFF_XT + (k + 3) * 64 + lane];
#pragma unroll
        for (int uu = 0; uu < 2; ++uu)
#pragma unroll
            for (int g = 0; g < 4; ++g)
                acc[uu][g] += dot4(*(const float4*)&Wih[(size_t)(g * 512 + u0 + uu) * 576 + k], xv);
    }
#pragma unroll
    for (int uu = 0; uu < 2; ++uu)
#pragma unroll
        for (int g = 0; g < 4; ++g)
            gpart[((w * 2 + uu) * 4 + g) * 64 + lane] = acc[uu][g];
    __syncthreads();
    if (tid < 128) {
        int uu = tid >> 6, b = tid & 63;
        int u = u0 + uu;
        float g4[4];
#pragma unroll
        for (int g = 0; g < 4; ++g) {
            float s = ws[OFF_GHH + (size_t)(g * 512 + u) * 64 + b];
#pragma unroll
            for (int ww = 0; ww < 8; ++ww) s += gpart[((ww * 2 + uu) * 4 + g) * 64 + b];
            g4[g] = s;
        }
        int idx = u * 64 + b;
        float co = ws[OFF_CS + idx];
        float I = sigf(g4[0]), F = sigf(g4[1]), G = tanhf(g4[2]), O = sigf(g4[3]);
        float cn = F * co + I * G;
        ws[OFF_CS + idx] = cn;
        ws[OFF_XT + (size_t)(576 + u) * 64 + b] = O * tanhf(cn);
    }
}

// ---------------- fused: hh partial (blocks 0..255) + bf16 attn (blocks 256..2303) --
// hh: ghh = Whh@hs + bih + bhh (for next step). attn: as R11, hs fixed at rows 576.
__global__ __launch_bounds__(256) void k_hh_attn(const int* __restrict__ slen,
                                                 const float* __restrict__ Whh,
                                                 const float* __restrict__ bih,
                                                 const float* __restrict__ bhh,
                                                 float* __restrict__ ws) {
    const int blk = blockIdx.x;
    const int tid = threadIdx.x;
    const int lane = tid & 63;
    __shared__ float smem[2048];   // hh: gpart[4][2][4][64]; attn: hs/e/wt arenas
    if (blk < 256) {
        // ---- hh body ----
        const int w = tid >> 6;
        const int u0 = blk * 2;
        const int wq = __builtin_amdgcn_readfirstlane(w);
        float acc[2][4] = {{0, 0, 0, 0}, {0, 0, 0, 0}};
        int k0 = wq * 128, k1 = k0 + 128;
#pragma unroll 2
        for (int k = k0; k < k1; k += 4) {
            float4 xv;
            xv.x = ws[OFF_XT + (576 + k + 0) * 64 + lane];
            xv.y = ws[OFF_XT + (576 + k + 1) * 64 + lane];
            xv.z = ws[OFF_XT + (576 + k + 2) * 64 + lane];
            xv.w = ws[OFF_XT + (576 + k + 3) * 64 + lane];
#pragma unroll
            for (int uu = 0; uu < 2; ++uu)
#pragma unroll
                for (int g = 0; g < 4; ++g)
                    acc[uu][g] += dot4(*(const float4*)&Whh[(size_t)(g * 512 + u0 + uu) * 512 + k], xv);
        }
#pragma unroll
        for (int uu = 0; uu < 2; ++uu)
#pragma unroll
            for (int g = 0; g < 4; ++g)
                smem[((w * 2 + uu) * 4 + g) * 64 + lane] = acc[uu][g];
        __syncthreads();
        if (tid < 128) {
            int uu = tid >> 6, b = tid & 63;
            int u = u0 + uu;
#pragma unroll
            for (int g = 0; g < 4; ++g) {
                int r = g * 512 + u;
                float s = bih[r] + bhh[r];
#pragma unroll
                for (int ww = 0; ww < 4; ++ww) s += smem[((ww * 2 + uu) * 4 + g) * 64 + b];
                ws[OFF_GHH + (size_t)r * 64 + b] = s;
            }
        }
        return;
    }
    // ---- attn body ----
    float* hs_sh  = smem;          // [512]
    float* e_part = smem + 512;    // [128]
    float* e_sh   = smem + 640;    // [32]
    float* wt_sh  = smem + 672;    // [32]
    const int ab = blk - 256;
    const int w = __builtin_amdgcn_readfirstlane(tid >> 6);
    const int rg = lane >> 4, cl = lane & 15;
    const int b = ab >> 5, sb = ab & 31;
    const int L = slen[b];
    const int t0 = sb * 32;
    const ushort_t* hb = (const ushort_t*)(ws + OFF_HB16F)
                       + ((size_t)b * 1024 + t0) * 512 + w * 128 + cl * 8;
    uint4 r0 = *(const uint4*)(hb + (size_t)(rg * 8 + 0) * 512);
    uint4 r1 = *(const uint4*)(hb + (size_t)(rg * 8 + 1) * 512);
    uint4 r2 = *(const uint4*)(hb + (size_t)(rg * 8 + 2) * 512);
    uint4 r3 = *(const uint4*)(hb + (size_t)(rg * 8 + 3) * 512);
    uint4 r4 = *(const uint4*)(hb + (size_t)(rg * 8 + 4) * 512);
    uint4 r5 = *(const uint4*)(hb + (size_t)(rg * 8 + 5) * 512);
    uint4 r6 = *(const uint4*)(hb + (size_t)(rg * 8 + 6) * 512);
    uint4 r7 = *(const uint4*)(hb + (size_t)(rg * 8 + 7) * 512);
    hs_sh[tid]       = ws[OFF_XT + (size_t)(576 + tid) * 64 + b];
    hs_sh[256 + tid] = ws[OFF_XT + (size_t)(576 + 256 + tid) * 64 + b];
    __syncthreads();
    float hsv[8];
#pragma unroll
    for (int j = 0; j < 8; ++j) hsv[j] = hs_sh[w * 128 + cl * 8 + j];
#define EROW(J, R)                                                                  \
    {                                                                               \
        float part = BLO(R.x) * hsv[0] + BHI(R.x) * hsv[1]                          \
                   + BLO(R.y) * hsv[2] + BHI(R.y) * hsv[3]                          \
                   + BLO(R.z) * hsv[4] + BHI(R.z) * hsv[5]                          \
                   + BLO(R.w) * hsv[6] + BHI(R.w) * hsv[7];                         \
        part += __shfl_xor(part, 1);                                                \
        part += __shfl_xor(part, 2);                                                \
        part += __shfl_xor(part, 4);                                                \
        part += __shfl_xor(part, 8);                                                \
        if (cl == 0) e_part[w * 32 + rg * 8 + (J)] = part;                          \
    }
    EROW(0, r0) EROW(1, r1) EROW(2, r2) EROW(3, r3)
    EROW(4, r4) EROW(5, r5) EROW(6, r6) EROW(7, r7)
#undef EROW
    __syncthreads();
    if (tid < 32) {
        float e = e_part[tid] + e_part[32 + tid] + e_part[64 + tid] + e_part[96 + tid];
        e_sh[tid] = e;
        ws[OFF_E + (size_t)b * 1024 + t0 + tid] = e;
    }
    __syncthreads();
    if (tid < 32) {
        float m = e_sh[0];
#pragma unroll
        for (int j = 1; j < 32; ++j) m = fmaxf(m, e_sh[j]);
        int tg = t0 + tid;
        wt_sh[tid] = (tg < L) ? __expf(e_sh[tid] - m) : 0.0f;
        if (tid == 0) ws[OFF_MD + (b * 32 + sb) * 2] = m;
    }
    __syncthreads();
    int nr = L - t0;
    nr = nr < 0 ? 0 : (nr > 32 ? 32 : nr);
    if (nr > 0) {                                  // fully-masked slices: skip PV+CP
        float acc[8] = {0, 0, 0, 0, 0, 0, 0, 0};
#define PVROW(J, R)                                                                 \
        {                                                                           \
            float wt = wt_sh[rg * 8 + (J)];                                         \
            acc[0] += wt * BLO(R.x); acc[1] += wt * BHI(R.x);                       \
            acc[2] += wt * BLO(R.y); acc[3] += wt * BHI(R.y);                       \
            acc[4] += wt * BLO(R.z); acc[5] += wt * BHI(R.z);                       \
            acc[6] += wt * BLO(R.w); acc[7] += wt * BHI(R.w);                       \
        }
        PVROW(0, r0) PVROW(1, r1) PVROW(2, r2) PVROW(3, r3)
        PVROW(4, r4) PVROW(5, r5) PVROW(6, r6) PVROW(7, r7)
#undef PVROW
#pragma unroll
        for (int k = 0; k < 8; ++k) {
            acc[k] += __shfl_xor(acc[k], 16);
            acc[k] += __shfl_xor(acc[k], 32);
        }
        if (rg == 0) {
            float4 o0; o0.x = acc[0]; o0.y = acc[1]; o0.z = acc[2]; o0.w = acc[3];
            float4 o1; o1.x = acc[4]; o1.y = acc[5]; o1.z = acc[6]; o1.w = acc[7];
            float* cp = ws + OFF_CP + (size_t)(b * 32 + sb) * 512 + w * 128 + cl * 8;
            *(float4*)cp = o0;
            *(float4*)(cp + 4) = o1;
        }
    }
    if (tid == 0) {
        float D = 0.0f;
#pragma unroll
        for (int tl = 0; tl < 32; ++tl) D += wt_sh[tl];
        ws[OFF_MD + (b * 32 + sb) * 2 + 1] = D;
    }
}

// ---------------- comb: global max + ctx + attentions + head + lens + x ----------
// grid 64 x 512
__global__ __launch_bounds__(512) void k_comb2(const int* __restrict__ slen,
                                               float* __restrict__ ws,
                                               float* __restrict__ out, int ts) {
    const int b = blockIdx.x, tid = threadIdx.x;
    __shared__ float red[512];
    __shared__ float feat[1024];
    __shared__ float sc_sh[32];
    __shared__ float lg_s[64];
    float mx = -INFINITY;
#pragma unroll
    for (int i = 0; i < 4; ++i) mx = fmaxf(mx, ws[OFF_MD + (tid + 512 * i) * 2]);
    red[tid] = mx;
    __syncthreads();
    for (int s = 256; s > 0; s >>= 1) {
        if (tid < s) red[tid] = fmaxf(red[tid], red[tid + s]);
        __syncthreads();
    }
    float m_g = red[0];
    __syncthreads();
    int L = slen[b];
    int nsl = (L + 31) >> 5;                      // slices with any live rows
    if (tid < 32) {
        float s = 0.0f, sd = 0.0f;
        if (tid < nsl) {
            float mi = ws[OFF_MD + (b * 32 + tid) * 2];
            float Di = ws[OFF_MD + (b * 32 + tid) * 2 + 1];
            s = __expf(mi - m_g);
            sd = s * Di;
        }
        sc_sh[tid] = s;
        red[tid] = sd;
    }
    __syncthreads();
    float dn = 0.0f;
#pragma unroll
    for (int j = 0; j < 32; ++j) dn += red[j];
    float inv = 1.0f / (dn + 1e-5f);
    float cx = 0.0f;
    for (int i = 0; i < nsl; ++i)
        cx += sc_sh[i] * ws[OFF_CP + (size_t)(b * 32 + i) * 512 + tid];
    cx *= inv;
    feat[512 + tid] = cx;
    ws[OFF_XT + (size_t)(64 + tid) * 64 + b] = cx;
    feat[tid] = ws[OFF_XT + (size_t)(576 + tid) * 64 + b];
#pragma unroll
    for (int q = 0; q < 2; ++q) {
        int t = tid + 512 * q;
        float e = ws[OFF_E + (size_t)b * 1024 + t];
        float a = (t < L) ? __expf(e - m_g) * inv : 0.0f;
        out[OUT_ATT + (size_t)b * 131072 + (size_t)ts * 1024 + t] = a;
    }
    __syncthreads();
    int v = tid >> 3, qq = tid & 7;
    const float4* w4 = (const float4*)(ws + OFF_W2 + (size_t)v * 1024 + qq * 128);
    const float4* f4 = (const float4*)feat + qq * 32;
    float acc = 0.0f;
#pragma unroll 8
    for (int k = 0; k < 32; ++k) acc += dot4(w4[k], f4[k]);
    acc += __shfl_xor(acc, 1);
    acc += __shfl_xor(acc, 2);
    acc += __shfl_xor(acc, 4);
    if (qq == 0) lg_s[v] = acc;
    __syncthreads();
    if (tid < 64) {
        float lg = lg_s[tid] + ws[OFF_B2 + tid];
        float mxv = lg;
#pragma unroll
        for (int mm = 1; mm < 64; mm <<= 1) mxv = fmaxf(mxv, __shfl_xor(mxv, mm));
        float ev = __expf(lg - mxv);
        float s = ev;
#pragma unroll
        for (int mm = 1; mm < 64; mm <<= 1) s += __shfl_xor(s, mm);
        float y = ev / s;
        out[OUT_YH + (size_t)b * 8192 + ts * 64 + tid] = y;
        ws[OFF_XT + (size_t)tid * 64 + b] = y;
        float av = lg;
        int ai = tid;
#pragma unroll
        for (int mm = 1; mm < 64; mm <<= 1) {
            float ov = __shfl_xor(av, mm);
            int oi = __shfl_xor(ai, mm);
            if (ov > av || (ov == av && oi < ai)) { av = ov; ai = oi; }
        }
        if (tid == 0) {
            int* lens = (int*)ws + OFF_LENS;
            if (ai == 1 && lens[b] > ts) lens[b] = ts + 1;   // EOS == 1
            if (ts == 127) out[OUT_LENS + b] = (float)lens[b];
        }
    }
}

// ================= f32 fallback path (R11 kernels, ping-pong hs) =================
__global__ __launch_bounds__(1024) void k_gates(
        const float* __restrict__ Wih, const float* __restrict__ Whh,
        const float* __restrict__ bih, const float* __restrict__ bhh,
        float* __restrict__ ws, int p) {
    const int tid = threadIdx.x;
    const int lane = tid & 63;
    const int w = tid >> 6;
    const int hs_in  = 576 + (p ? 512 : 0);
    const int hs_out = 576 + (p ? 0 : 512);
    __shared__ float gpart[8192];
    const int u0 = blockIdx.x * 2;
    const int wq = __builtin_amdgcn_readfirstlane(w);
    float acc[2][4] = {{0, 0, 0, 0}, {0, 0, 0, 0}};
    int k0 = wq * 68, k1 = k0 + 68;
    int kx1 = k1 < 576 ? k1 : 576;
#pragma unroll 2
    for (int k = k0; k < kx1; k += 4) {
        float4 xv;
        xv.x = ws[OFF_XT + (k + 0) * 64 + lane];
        xv.y = ws[OFF_XT + (k + 1) * 64 + lane];
        xv.z = ws[OFF_XT + (k + 2) * 64 + lane];
        xv.w = ws[OFF_XT + (k + 3) * 64 + lane];
#pragma unroll
        for (int uu = 0; uu < 2; ++uu)
#pragma unroll
            for (int g = 0; g < 4; ++g)
                acc[uu][g] += dot4(*(const float4*)&Wih[(size_t)(g * 512 + u0 + uu) * 576 + k], xv);
    }
    int kh0 = k0 > 576 ? k0 : 576;
#pragma unroll 2
    for (int k = kh0; k < k1; k += 4) {
        float4 xv;
        xv.x = ws[OFF_XT + (hs_in + (k - 576) + 0) * 64 + lane];
        xv.y = ws[OFF_XT + (hs_in + (k - 576) + 1) * 64 + lane];
        xv.z = ws[OFF_XT + (hs_in + (k - 576) + 2) * 64 + lane];
        xv.w = ws[OFF_XT + (hs_in + (k - 576) + 3) * 64 + lane];
#pragma unroll
        for (int uu = 0; uu < 2; ++uu)
#pragma unroll
            for (int g = 0; g < 4; ++g)
                acc[uu][g] += dot4(*(const float4*)&Whh[(size_t)(g * 512 + u0 + uu) * 512 + (k - 576)], xv);
    }
#pragma unroll
    for (int uu = 0; uu < 2; ++uu)
#pragma unroll
        for (int g = 0; g < 4; ++g)
            gpart[((w * 2 + uu) * 4 + g) * 64 + lane] = acc[uu][g];
    __syncthreads();
    if (tid < 128) {
        int uu = tid >> 6, b = tid & 63;
        int u = u0 + uu;
        float g4[4];
#pragma unroll
        for (int g = 0; g < 4; ++g) {
            float s = 0.0f;
#pragma unroll
            for (int ww = 0; ww < 16; ++ww) s += gpart[((ww * 2 + uu) * 4 + g) * 64 + b];
            g4[g] = s + bih[g * 512 + u] + bhh[g * 512 + u];
        }
        int idx = u * 64 + b;
        float co = ws[OFF_CS + idx];
        float I = sigf(g4[0]), F = sigf(g4[1]), G = tanhf(g4[2]), O = sigf(g4[3]);
        float cn = F * co + I * G;
        ws[OFF_CS + idx] = cn;
        ws[OFF_XT + (size_t)(hs_out + u) * 64 + b] = O * tanhf(cn);
    }
}

__global__ void k_attn(const float* __restrict__ h, const int* __restrict__ slen,
                       float* __restrict__ ws, int p) {
    const int blk = blockIdx.x;
    const int tid = threadIdx.x;
    const int lane = tid & 63;
    const int w = tid >> 6;
    const int hs_out = 576 + (p ? 0 : 512);
    const int b = blk >> 4, sb = blk & 15;
    const int L = slen[b];
    const int t0 = sb * 64;
    __shared__ float stage[4096];
    __shared__ float hs_sh[512];
    __shared__ float e_sh[8];
    const float* hb = h + ((size_t)b * 1024 + t0) * 512;
    hs_sh[tid]       = ws[OFF_XT + (size_t)(hs_out + tid) * 64 + b];
    hs_sh[256 + tid] = ws[OFF_XT + (size_t)(hs_out + 256 + tid) * 64 + b];
    __syncthreads();
    float hsv[8];
#pragma unroll
    for (int j = 0; j < 8; ++j) hsv[j] = hs_sh[lane * 8 + j];
    float m_run = -INFINITY, D = 0.0f, accx = 0.0f, accy = 0.0f;
    for (int c = 0; c < 8; ++c) {
        const float* gsrc = hb + (size_t)c * 4096 + tid * 4;
        float4 tv0 = *(const float4*)(gsrc);
        float4 tv1 = *(const float4*)(gsrc + 1024);
        float4 tv2 = *(const float4*)(gsrc + 2048);
        float4 tv3 = *(const float4*)(gsrc + 3072);
        __syncthreads();
        *(float4*)&stage[tid * 4]        = tv0;
        *(float4*)&stage[1024 + tid * 4] = tv1;
        *(float4*)&stage[2048 + tid * 4] = tv2;
        *(float4*)&stage[3072 + tid * 4] = tv3;
        __syncthreads();
#pragma unroll
        for (int rr = 0; rr < 2; ++rr) {
            int tl = w * 2 + rr;
            const float4* rp = (const float4*)&stage[tl * 512 + lane * 8];
            float4 pp = rp[0], qq = rp[1];
            float part = pp.x * hsv[0] + pp.y * hsv[1] + pp.z * hsv[2] + pp.w * hsv[3]
                       + qq.x * hsv[4] + qq.y * hsv[5] + qq.z * hsv[6] + qq.w * hsv[7];
#pragma unroll
            for (int mm = 1; mm < 64; mm <<= 1) part += __shfl_xor(part, mm);
            if (lane == 0) {
                e_sh[tl] = part;
                ws[OFF_E + (size_t)b * 1024 + t0 + c * 8 + tl] = part;
            }
        }
        __syncthreads();
        float cm = e_sh[0];
#pragma unroll
        for (int j = 1; j < 8; ++j) cm = fmaxf(cm, e_sh[j]);
        float m_new = fmaxf(m_run, cm);
        float sc = __expf(m_run - m_new);
        accx *= sc; accy *= sc; D *= sc;
        m_run = m_new;
#pragma unroll
        for (int tl = 0; tl < 8; ++tl) {
            int tg = t0 + c * 8 + tl;
            float wt = (tg < L) ? __expf(e_sh[tl] - m_run) : 0.0f;
            D += wt;
            float2 hv = *(const float2*)&stage[tl * 512 + tid * 2];
            accx += wt * hv.x;
            accy += wt * hv.y;
        }
    }
    float2 o2; o2.x = accx; o2.y = accy;
    *(float2*)&ws[OFF_CP + (size_t)(b * 16 + sb) * 512 + tid * 2] = o2;
    if (tid == 0) {
        ws[OFF_MD + (b * 16 + sb) * 2]     = m_run;
        ws[OFF_MD + (b * 16 + sb) * 2 + 1] = D;
    }
}

__global__ void k_comb(const int* __restrict__ slen, float* __restrict__ ws,
                       float* __restrict__ out, int p, int ts, int ns) {
    const int b = blockIdx.x, tid = threadIdx.x;
    const int hs_out = 576 + (p ? 0 : 512);
    __shared__ float red[256];
    __shared__ float feat[1024];
    __shared__ float sc_sh[32];
    __shared__ float lg_s[64];
    const int nent = 64 * ns;
    float mx = -INFINITY;
    for (int i = tid; i < nent; i += 256) mx = fmaxf(mx, ws[OFF_MD + i * 2]);
    red[tid] = mx;
    __syncthreads();
    for (int s = 128; s > 0; s >>= 1) {
        if (tid < s) red[tid] = fmaxf(red[tid], red[tid + s]);
        __syncthreads();
    }
    float m_g = red[0];
    __syncthreads();
    if (tid < ns) {
        float mi = ws[OFF_MD + (b * ns + tid) * 2];
        float Di = ws[OFF_MD + (b * ns + tid) * 2 + 1];
        float s = __expf(mi - m_g);
        sc_sh[tid] = s;
        red[tid] = s * Di;
    }
    __syncthreads();
    float dn = 0.0f;
    for (int j = 0; j < ns; ++j) dn += red[j];
    float inv = 1.0f / (dn + 1e-5f);
    float cx = 0.0f, cy = 0.0f;
    for (int i = 0; i < ns; ++i) {
        float s = sc_sh[i];
        float2 v = *(const float2*)&ws[OFF_CP + (size_t)(b * ns + i) * 512 + tid * 2];
        cx += s * v.x;
        cy += s * v.y;
    }
    cx *= inv; cy *= inv;
    feat[512 + tid * 2] = cx;
    feat[512 + tid * 2 + 1] = cy;
    ws[OFF_XT + (size_t)(64 + tid * 2) * 64 + b] = cx;
    ws[OFF_XT + (size_t)(64 + tid * 2 + 1) * 64 + b] = cy;
    feat[tid * 2]     = ws[OFF_XT + (size_t)(hs_out + tid * 2) * 64 + b];
    feat[tid * 2 + 1] = ws[OFF_XT + (size_t)(hs_out + tid * 2 + 1) * 64 + b];
    int L = slen[b];
#pragma unroll
    for (int q = 0; q < 4; ++q) {
        int t = tid + 256 * q;
        float e = ws[OFF_E + (size_t)b * 1024 + t];
        float a = (t < L) ? __expf(e - m_g) * inv : 0.0f;
        out[OUT_ATT + (size_t)b * 131072 + (size_t)ts * 1024 + t] = a;
    }
    __syncthreads();
    int v = tid >> 2, qq = tid & 3;
    const float4* w4 = (const float4*)(ws + OFF_W2 + (size_t)v * 1024 + qq * 256);
    const float4* f4 = (const float4*)feat + qq * 64;
    float acc = 0.0f;
#pragma unroll 8
    for (int k = 0; k < 64; ++k) acc += dot4(w4[k], f4[k]);
    acc += __shfl_xor(acc, 1);
    acc += __shfl_xor(acc, 2);
    if (qq == 0) lg_s[v] = acc;
    __syncthreads();
    if (tid < 64) {
        float lg = lg_s[tid] + ws[OFF_B2 + tid];
        float mxv = lg;
#pragma unroll
        for (int mm = 1; mm < 64; mm <<= 1) mxv = fmaxf(mxv, __shfl_xor(mxv, mm));
        float ev = __expf(lg - mxv);
        float s = ev;
#pragma unroll
        for (int mm = 1; mm < 64; mm <<= 1) s += __shfl_xor(s, mm);
        float y = ev / s;
        out[OUT_YH + (size_t)b * 8192 + ts * 64 + tid] = y;
        ws[OFF_XT + (size_t)tid * 64 + b] = y;
        float av = lg;
        int ai = tid;
#pragma unroll
        for (int mm = 1; mm < 64; mm <<= 1) {
            float ov = __shfl_xor(av, mm);
            int oi = __shfl_xor(ai, mm);
            if (ov > av || (ov == av && oi < ai)) { av = ov; ai = oi; }
        }
        if (tid == 0) {
            int* lens = (int*)ws + OFF_LENS;
            if (ai == 1 && lens[b] > ts) lens[b] = ts + 1;   // EOS == 1
            if (ts == 127) out[OUT_LENS + b] = (float)lens[b];
        }
    }
}

extern "C" void kernel_launch(void* const* d_in, const int* in_sizes, int n_in,
                              void* d_out, int out_size, void* d_ws, size_t ws_size,
                              hipStream_t stream) {
    (void)in_sizes; (void)n_in; (void)out_size;
    const float* h    = (const float*)d_in[0];
    const float* Wih  = (const float*)d_in[1];
    const float* Whh  = (const float*)d_in[2];
    const float* bih  = (const float*)d_in[3];
    const float* bhh  = (const float*)d_in[4];
    const float* fc1w = (const float*)d_in[5];
    const float* fc1b = (const float*)d_in[6];
    const float* fc2w = (const float*)d_in[7];
    const int*   slen = (const int*)d_in[8];
    float* ws  = (float*)d_ws;
    float* out = (float*)d_out;
    const bool use16 = (ws_size >= WS_NEED);

    k_init<<<528, 256, 0, stream>>>(h, ws);
    k_fuse<<<256, 256, 0, stream>>>(fc1w, fc1b, fc2w, bih, bhh, ws);
    if (use16) {
        k_hconv<<<16384, 256, 0, stream>>>(h, ws);
        for (int t = 0; t < 128; t++) {
            k_gatesx<<<256, 512, 0, stream>>>(Wih, ws);
            k_hh_attn<<<2304, 256, 0, stream>>>(slen, Whh, bih, bhh, ws);
            k_comb2<<<64, 512, 0, stream>>>(slen, ws, out, t);
        }
    } else {
        for (int t = 0; t < 128; t++) {
            int p = t & 1;
            k_gates<<<256, 1024, 0, stream>>>(Wih, Whh, bih, bhh, ws, p);
            k_attn<<<1024, 256, 0, stream>>>(h, slen, ws, p);
            k_comb<<<64, 256, 0, stream>>>(slen, ws, out, p, t, 16);
        }
    }
}